// Round 1
// baseline (10372.092 us; speedup 1.0000x reference)
//
#include <hip/hip_runtime.h>
#include <math.h>

#define NN 512
#define ND 64
#define ED 32
#define HD 128
#define NHD 4
#define JT 16
#define K1 161

__device__ __forceinline__ float silu_f(float v) { return v / (1.f + __expf(-v)); }

__device__ __forceinline__ float block_sum(float v, float* s_red, int t) {
    s_red[t] = v;
    __syncthreads();
    for (int s = 128; s > 0; s >>= 1) {
        if (t < s) s_red[t] += s_red[t + s];
        __syncthreads();
    }
    float r = s_red[0];
    __syncthreads();
    return r;
}

// LayerNorm over rows of a [JT][128] LDS tile. t -> (row lj = t>>4, lane ll = t&15), 8 elems each.
__device__ __forceinline__ void tile_ln128(float (*s)[HD], const float* g, const float* bb,
                                           int lj, int ll) {
    float vals[8];
#pragma unroll
    for (int r = 0; r < 8; r++) vals[r] = s[lj][ll + 16 * r];
    float sm = vals[0] + vals[1] + vals[2] + vals[3] + vals[4] + vals[5] + vals[6] + vals[7];
    sm += __shfl_xor(sm, 8); sm += __shfl_xor(sm, 4); sm += __shfl_xor(sm, 2); sm += __shfl_xor(sm, 1);
    float mean = sm * 0.0078125f;
    float sq = 0.f;
#pragma unroll
    for (int r = 0; r < 8; r++) { float d = vals[r] - mean; sq += d * d; }
    sq += __shfl_xor(sq, 8); sq += __shfl_xor(sq, 4); sq += __shfl_xor(sq, 2); sq += __shfl_xor(sq, 1);
    float rstd = rsqrtf(sq * 0.0078125f + 1e-5f);
#pragma unroll
    for (int r = 0; r < 8; r++) {
        int c = ll + 16 * r;
        s[lj][c] = (vals[r] - mean) * rstd * g[c] + bb[c];
    }
}

extern "C" __global__ __launch_bounds__(256)
void egnn_fused(const float* __restrict__ h, const float* __restrict__ x, const float* __restrict__ e,
                const float* __restrict__ msg_W1, const float* __restrict__ msg_b1,
                const float* __restrict__ msg_ln_g, const float* __restrict__ msg_ln_b,
                const float* __restrict__ msg_W2, const float* __restrict__ msg_b2,
                const float* __restrict__ msg_W3, const float* __restrict__ msg_b3,
                const float* __restrict__ attn_W1, const float* __restrict__ attn_b1,
                const float* __restrict__ attn_W2, const float* __restrict__ attn_b2,
                const float* __restrict__ val_W, const float* __restrict__ val_b,
                const float* __restrict__ coord_W1, const float* __restrict__ coord_b1,
                const float* __restrict__ coord_W2,
                const float* __restrict__ node_W1, const float* __restrict__ node_b1,
                const float* __restrict__ node_ln_g, const float* __restrict__ node_ln_b,
                const float* __restrict__ node_W2, const float* __restrict__ node_b2,
                const float* __restrict__ edge_W1, const float* __restrict__ edge_b1,
                const float* __restrict__ edge_ln_g, const float* __restrict__ edge_ln_b,
                const float* __restrict__ edge_W2, const float* __restrict__ edge_b2,
                const float* __restrict__ nn_g, const float* __restrict__ nn_b,
                const float* __restrict__ en_g, const float* __restrict__ en_b,
                const float* __restrict__ coord_scale_p,
                float* __restrict__ out_h, float* __restrict__ out_x, float* __restrict__ out_e) {
    const int t = threadIdx.x;
    const int bi = blockIdx.x;    // b*NN + i
    const int b = bi >> 9;
    // const int i = bi & 511;   // not needed separately

    __shared__ float s_in[JT][168];   // [0:64)=h_i  [64:128)=h_j  [128:160)=e_ij  [160]=dist
    __shared__ float s_a[JT][HD];
    __shared__ float s_b[JT][HD];
    __shared__ float s_msg[JT][HD];
    __shared__ float s_v[JT][HD];
    __shared__ float s_logit[JT][NHD];
    __shared__ float s_dist[JT];
    __shared__ float s_xdn[JT][2];
    __shared__ float s_hi[ND];
    __shared__ float s_hin[ND + HD];
    __shared__ float s_nh[HD];
    __shared__ float s_red[256];

    if (t < ND) s_hi[t] = h[(size_t)bi * ND + t];
    const float xi0 = x[(size_t)bi * 2 + 0];
    const float xi1 = x[(size_t)bi * 2 + 1];
    __syncthreads();

    // prefill the h_i part of msg_input (constant across tiles)
    for (int idx = t; idx < JT * ND; idx += 256) {
        int j = idx >> 6, k = idx & 63;
        s_in[j][k] = s_hi[k];
    }

    // online softmax state (valid for t<128)
    float m_run = -1e30f, l_run = 0.f, acc_run = 0.f;
    const int sm_hd = t >> 5, sm_d = t & 31;

    // coord accumulators (valid for t<16)
    float cu_x = 0.f, cu_y = 0.f;

    const int o128 = t & 127, jh = t >> 7;  // O=128 GEMMs: 8 j's per thread
    const int o64 = t & 63,  jq = t >> 6;   // O=64 GEMMs: 4 j's per thread
    const int o32 = t & 31,  jg = t >> 5;   // O=32 GEMM: 2 j's per thread
    const int lj = t >> 4,   ll = t & 15;   // LN mapping

    for (int j0 = 0; j0 < NN; j0 += JT) {
        // ---- geometry ----
        if (t < JT) {
            int jj = j0 + t;
            float dx = x[((size_t)b * NN + jj) * 2 + 0] - xi0;
            float dy = x[((size_t)b * NN + jj) * 2 + 1] - xi1;
            float d = sqrtf(dx * dx + dy * dy);
            s_dist[t] = d;
            float inv = 1.f / (d + 1e-8f);
            s_xdn[t][0] = dx * inv;
            s_xdn[t][1] = dy * inv;
        }
        __syncthreads();
        // ---- stage h_j, e_ij, dist ----
        for (int j = 0; j < JT; j++) {
            int jj = j0 + j;
            if (t < 64)        s_in[j][64 + t]        = h[((size_t)b * NN + jj) * ND + t];
            else if (t < 96)   s_in[j][128 + (t - 64)] = e[(((size_t)bi) * NN + jj) * ED + (t - 64)];
            else if (t == 96)  s_in[j][160] = s_dist[j];
        }
        __syncthreads();

        // ---- GEMM1: (16x161)@(161x128) + b1, silu -> s_a ----
        {
            float acc[8] = {0, 0, 0, 0, 0, 0, 0, 0};
            for (int k4 = 0; k4 < 40; k4++) {
                int k = k4 * 4;
                float w0 = msg_W1[(k + 0) * HD + o128];
                float w1 = msg_W1[(k + 1) * HD + o128];
                float w2 = msg_W1[(k + 2) * HD + o128];
                float w3 = msg_W1[(k + 3) * HD + o128];
#pragma unroll
                for (int u = 0; u < 8; u++) {
                    float4 iv = *(const float4*)&s_in[jh * 8 + u][k];
                    acc[u] = fmaf(iv.x, w0, acc[u]);
                    acc[u] = fmaf(iv.y, w1, acc[u]);
                    acc[u] = fmaf(iv.z, w2, acc[u]);
                    acc[u] = fmaf(iv.w, w3, acc[u]);
                }
            }
            {   // tail k = 160
                float w = msg_W1[160 * HD + o128];
#pragma unroll
                for (int u = 0; u < 8; u++) acc[u] = fmaf(s_in[jh * 8 + u][160], w, acc[u]);
            }
            float bb = msg_b1[o128];
#pragma unroll
            for (int u = 0; u < 8; u++) s_a[jh * 8 + u][o128] = silu_f(acc[u] + bb);
        }
        __syncthreads();
        tile_ln128(s_a, msg_ln_g, msg_ln_b, lj, ll);
        __syncthreads();

        // ---- GEMM2: silu(s_a @ msg_W2 + b2) -> s_b ----
        {
            float acc[8] = {0, 0, 0, 0, 0, 0, 0, 0};
            for (int k4 = 0; k4 < 32; k4++) {
                int k = k4 * 4;
                float w0 = msg_W2[(k + 0) * HD + o128];
                float w1 = msg_W2[(k + 1) * HD + o128];
                float w2 = msg_W2[(k + 2) * HD + o128];
                float w3 = msg_W2[(k + 3) * HD + o128];
#pragma unroll
                for (int u = 0; u < 8; u++) {
                    float4 iv = *(const float4*)&s_a[jh * 8 + u][k];
                    acc[u] = fmaf(iv.x, w0, acc[u]);
                    acc[u] = fmaf(iv.y, w1, acc[u]);
                    acc[u] = fmaf(iv.z, w2, acc[u]);
                    acc[u] = fmaf(iv.w, w3, acc[u]);
                }
            }
            float bb = msg_b2[o128];
#pragma unroll
            for (int u = 0; u < 8; u++) s_b[jh * 8 + u][o128] = silu_f(acc[u] + bb);
        }
        __syncthreads();

        // ---- GEMM3: s_b @ msg_W3 + b3 -> s_msg ----
        {
            float acc[8] = {0, 0, 0, 0, 0, 0, 0, 0};
            for (int k4 = 0; k4 < 32; k4++) {
                int k = k4 * 4;
                float w0 = msg_W3[(k + 0) * HD + o128];
                float w1 = msg_W3[(k + 1) * HD + o128];
                float w2 = msg_W3[(k + 2) * HD + o128];
                float w3 = msg_W3[(k + 3) * HD + o128];
#pragma unroll
                for (int u = 0; u < 8; u++) {
                    float4 iv = *(const float4*)&s_b[jh * 8 + u][k];
                    acc[u] = fmaf(iv.x, w0, acc[u]);
                    acc[u] = fmaf(iv.y, w1, acc[u]);
                    acc[u] = fmaf(iv.z, w2, acc[u]);
                    acc[u] = fmaf(iv.w, w3, acc[u]);
                }
            }
            float bb = msg_b3[o128];
#pragma unroll
            for (int u = 0; u < 8; u++) s_msg[jh * 8 + u][o128] = acc[u] + bb;
        }
        __syncthreads();

        // ---- values: s_msg @ val_W + val_b -> s_v ----
        {
            float acc[8] = {0, 0, 0, 0, 0, 0, 0, 0};
            for (int k4 = 0; k4 < 32; k4++) {
                int k = k4 * 4;
                float w0 = val_W[(k + 0) * HD + o128];
                float w1 = val_W[(k + 1) * HD + o128];
                float w2 = val_W[(k + 2) * HD + o128];
                float w3 = val_W[(k + 3) * HD + o128];
#pragma unroll
                for (int u = 0; u < 8; u++) {
                    float4 iv = *(const float4*)&s_msg[jh * 8 + u][k];
                    acc[u] = fmaf(iv.x, w0, acc[u]);
                    acc[u] = fmaf(iv.y, w1, acc[u]);
                    acc[u] = fmaf(iv.z, w2, acc[u]);
                    acc[u] = fmaf(iv.w, w3, acc[u]);
                }
            }
            float bb = val_b[o128];
#pragma unroll
            for (int u = 0; u < 8; u++) s_v[jh * 8 + u][o128] = acc[u] + bb;
        }
        // ---- attn hidden: silu(s_msg @ attn_W1 + b1) -> s_a[:, 0:64] ----
        {
            float acc[4] = {0, 0, 0, 0};
            for (int k4 = 0; k4 < 32; k4++) {
                int k = k4 * 4;
                float w0 = attn_W1[(k + 0) * 64 + o64];
                float w1 = attn_W1[(k + 1) * 64 + o64];
                float w2 = attn_W1[(k + 2) * 64 + o64];
                float w3 = attn_W1[(k + 3) * 64 + o64];
#pragma unroll
                for (int u = 0; u < 4; u++) {
                    float4 iv = *(const float4*)&s_msg[jq * 4 + u][k];
                    acc[u] = fmaf(iv.x, w0, acc[u]);
                    acc[u] = fmaf(iv.y, w1, acc[u]);
                    acc[u] = fmaf(iv.z, w2, acc[u]);
                    acc[u] = fmaf(iv.w, w3, acc[u]);
                }
            }
            float bb = attn_b1[o64];
#pragma unroll
            for (int u = 0; u < 4; u++) s_a[jq * 4 + u][o64] = silu_f(acc[u] + bb);
        }
        __syncthreads();

        // ---- logits: (16x64)@(64x4) + b2, /sqrt(32) ----
        if (t < 64) {
            int j = t >> 2, hd = t & 3;
            float acc = attn_b2[hd];
            for (int k = 0; k < 64; k++) acc = fmaf(s_a[j][k], attn_W2[k * NHD + hd], acc);
            s_logit[j][hd] = acc * 0.17677669529663687f;  // 1/sqrt(32)
        }
        __syncthreads();

        // ---- online softmax + value accumulation (t<128) ----
        if (t < 128) {
#pragma unroll
            for (int j = 0; j < JT; j++) {
                float lg = s_logit[j][sm_hd];
                float nm = fmaxf(m_run, lg);
                float sc = __expf(m_run - nm);
                float p = __expf(lg - nm);
                acc_run = acc_run * sc + p * s_v[j][sm_hd * 32 + sm_d];
                l_run = l_run * sc + p;
                m_run = nm;
            }
        }

        // ---- coord hidden: silu(s_msg @ coord_W1 + b1) -> s_b[:, 0:64] ----
        {
            float acc[4] = {0, 0, 0, 0};
            for (int k4 = 0; k4 < 32; k4++) {
                int k = k4 * 4;
                float w0 = coord_W1[(k + 0) * 64 + o64];
                float w1 = coord_W1[(k + 1) * 64 + o64];
                float w2 = coord_W1[(k + 2) * 64 + o64];
                float w3 = coord_W1[(k + 3) * 64 + o64];
#pragma unroll
                for (int u = 0; u < 4; u++) {
                    float4 iv = *(const float4*)&s_msg[jq * 4 + u][k];
                    acc[u] = fmaf(iv.x, w0, acc[u]);
                    acc[u] = fmaf(iv.y, w1, acc[u]);
                    acc[u] = fmaf(iv.z, w2, acc[u]);
                    acc[u] = fmaf(iv.w, w3, acc[u]);
                }
            }
            float bb = coord_b1[o64];
#pragma unroll
            for (int u = 0; u < 4; u++) s_b[jq * 4 + u][o64] = silu_f(acc[u] + bb);
        }
        __syncthreads();

        // ---- coord weight + accumulate (t<16) ----
        if (t < JT) {
            float acc = 0.f;
            for (int k = 0; k < 64; k++) acc = fmaf(s_b[t][k], coord_W2[k], acc);
            float cw = tanhf(acc * 0.1f);
            cu_x += cw * s_xdn[t][0];
            cu_y += cw * s_xdn[t][1];
        }

        // ---- edge hidden: silu([e | msg] @ edge_W1 + b1) -> s_a ----
        {
            float acc[8] = {0, 0, 0, 0, 0, 0, 0, 0};
            for (int k4 = 0; k4 < 8; k4++) {     // k = 0..31 : e part
                int k = k4 * 4;
                float w0 = edge_W1[(k + 0) * HD + o128];
                float w1 = edge_W1[(k + 1) * HD + o128];
                float w2 = edge_W1[(k + 2) * HD + o128];
                float w3 = edge_W1[(k + 3) * HD + o128];
#pragma unroll
                for (int u = 0; u < 8; u++) {
                    float4 iv = *(const float4*)&s_in[jh * 8 + u][128 + k];
                    acc[u] = fmaf(iv.x, w0, acc[u]);
                    acc[u] = fmaf(iv.y, w1, acc[u]);
                    acc[u] = fmaf(iv.z, w2, acc[u]);
                    acc[u] = fmaf(iv.w, w3, acc[u]);
                }
            }
            for (int k4 = 0; k4 < 32; k4++) {    // k = 32..159 : msg part
                int k = k4 * 4;
                float w0 = edge_W1[(32 + k + 0) * HD + o128];
                float w1 = edge_W1[(32 + k + 1) * HD + o128];
                float w2 = edge_W1[(32 + k + 2) * HD + o128];
                float w3 = edge_W1[(32 + k + 3) * HD + o128];
#pragma unroll
                for (int u = 0; u < 8; u++) {
                    float4 iv = *(const float4*)&s_msg[jh * 8 + u][k];
                    acc[u] = fmaf(iv.x, w0, acc[u]);
                    acc[u] = fmaf(iv.y, w1, acc[u]);
                    acc[u] = fmaf(iv.z, w2, acc[u]);
                    acc[u] = fmaf(iv.w, w3, acc[u]);
                }
            }
            float bb = edge_b1[o128];
#pragma unroll
            for (int u = 0; u < 8; u++) s_a[jh * 8 + u][o128] = silu_f(acc[u] + bb);
        }
        __syncthreads();
        tile_ln128(s_a, edge_ln_g, edge_ln_b, lj, ll);
        __syncthreads();

        // ---- ee: s_a @ edge_W2 + b2 + residual e -> s_b[:, 0:32] ----
        {
            float acc0 = 0.f, acc1 = 0.f;
            int ja = jg * 2, jb2 = jg * 2 + 1;
            for (int k4 = 0; k4 < 32; k4++) {
                int k = k4 * 4;
                float w0 = edge_W2[(k + 0) * ED + o32];
                float w1 = edge_W2[(k + 1) * ED + o32];
                float w2 = edge_W2[(k + 2) * ED + o32];
                float w3 = edge_W2[(k + 3) * ED + o32];
                float4 iva = *(const float4*)&s_a[ja][k];
                float4 ivb = *(const float4*)&s_a[jb2][k];
                acc0 = fmaf(iva.x, w0, acc0); acc0 = fmaf(iva.y, w1, acc0);
                acc0 = fmaf(iva.z, w2, acc0); acc0 = fmaf(iva.w, w3, acc0);
                acc1 = fmaf(ivb.x, w0, acc1); acc1 = fmaf(ivb.y, w1, acc1);
                acc1 = fmaf(ivb.z, w2, acc1); acc1 = fmaf(ivb.w, w3, acc1);
            }
            float bb = edge_b2[o32];
            s_b[ja][o32]  = acc0 + bb + s_in[ja][128 + o32];
            s_b[jb2][o32] = acc1 + bb + s_in[jb2][128 + o32];
        }
        __syncthreads();

        // ---- final edge LN (rows of 32) + write out ----
        {
            float v0 = s_b[lj][ll], v1 = s_b[lj][ll + 16];
            float sm = v0 + v1;
            sm += __shfl_xor(sm, 8); sm += __shfl_xor(sm, 4); sm += __shfl_xor(sm, 2); sm += __shfl_xor(sm, 1);
            float mean = sm * 0.03125f;
            float d0 = v0 - mean, d1 = v1 - mean;
            float sq = d0 * d0 + d1 * d1;
            sq += __shfl_xor(sq, 8); sq += __shfl_xor(sq, 4); sq += __shfl_xor(sq, 2); sq += __shfl_xor(sq, 1);
            float rstd = rsqrtf(sq * 0.03125f + 1e-5f);
            size_t base = (((size_t)bi) * NN + (j0 + lj)) * ED;
            out_e[base + ll]      = d0 * rstd * en_g[ll] + en_b[ll];
            out_e[base + ll + 16] = d1 * rstd * en_g[ll + 16] + en_b[ll + 16];
        }
        __syncthreads();
    }

    // ================= node & coord epilogue =================
    if (t < HD) s_hin[ND + t] = acc_run / l_run;  // messages_attended
    if (t < ND) s_hin[t] = s_hi[t];
    __syncthreads();

    if (t < HD) {
        float acc = node_b1[t];
        for (int k4 = 0; k4 < (ND + HD) / 4; k4++) {
            float4 iv = *(const float4*)&s_hin[k4 * 4];
            acc = fmaf(iv.x, node_W1[(k4 * 4 + 0) * HD + t], acc);
            acc = fmaf(iv.y, node_W1[(k4 * 4 + 1) * HD + t], acc);
            acc = fmaf(iv.z, node_W1[(k4 * 4 + 2) * HD + t], acc);
            acc = fmaf(iv.w, node_W1[(k4 * 4 + 3) * HD + t], acc);
        }
        s_nh[t] = silu_f(acc);
    }
    __syncthreads();

    {   // LN over 128 (node_ln)
        float v = (t < HD) ? s_nh[t] : 0.f;
        float mean = block_sum(v, s_red, t) * 0.0078125f;
        float d = (t < HD) ? (v - mean) : 0.f;
        float var = block_sum(d * d, s_red, t) * 0.0078125f;
        float rstd = rsqrtf(var + 1e-5f);
        if (t < HD) s_nh[t] = d * rstd * node_ln_g[t] + node_ln_b[t];
    }
    __syncthreads();

    if (t < ND) {
        float acc = node_b2[t];
        for (int k4 = 0; k4 < 32; k4++) {
            float4 iv = *(const float4*)&s_nh[k4 * 4];
            acc = fmaf(iv.x, node_W2[(k4 * 4 + 0) * ND + t], acc);
            acc = fmaf(iv.y, node_W2[(k4 * 4 + 1) * ND + t], acc);
            acc = fmaf(iv.z, node_W2[(k4 * 4 + 2) * ND + t], acc);
            acc = fmaf(iv.w, node_W2[(k4 * 4 + 3) * ND + t], acc);
        }
        s_hin[t] = acc + s_hi[t];  // residual (reuse s_hin low half)
    }
    __syncthreads();

    {   // final h LN over 64 (nn)
        float v = (t < ND) ? s_hin[t] : 0.f;
        float mean = block_sum(v, s_red, t) * 0.015625f;
        float d = (t < ND) ? (v - mean) : 0.f;
        float var = block_sum(d * d, s_red, t) * 0.015625f;
        float rstd = rsqrtf(var + 1e-5f);
        if (t < ND) out_h[(size_t)bi * ND + t] = d * rstd * nn_g[t] + nn_b[t];
    }

    // x update
    if (t < 16) {
        cu_x += __shfl_xor(cu_x, 8); cu_x += __shfl_xor(cu_x, 4);
        cu_x += __shfl_xor(cu_x, 2); cu_x += __shfl_xor(cu_x, 1);
        cu_y += __shfl_xor(cu_y, 8); cu_y += __shfl_xor(cu_y, 4);
        cu_y += __shfl_xor(cu_y, 2); cu_y += __shfl_xor(cu_y, 1);
        if (t == 0) {
            float scl = coord_scale_p[0];
            out_x[(size_t)bi * 2 + 0] = xi0 + scl * cu_x;
            out_x[(size_t)bi * 2 + 1] = xi1 + scl * cu_y;
        }
    }
}

extern "C" void kernel_launch(void* const* d_in, const int* in_sizes, int n_in,
                              void* d_out, int out_size, void* d_ws, size_t ws_size,
                              hipStream_t stream) {
    const float* h        = (const float*)d_in[0];
    const float* x        = (const float*)d_in[1];
    const float* e        = (const float*)d_in[2];
    const float* msg_W1   = (const float*)d_in[3];
    const float* msg_b1   = (const float*)d_in[4];
    const float* msg_ln_g = (const float*)d_in[5];
    const float* msg_ln_b = (const float*)d_in[6];
    const float* msg_W2   = (const float*)d_in[7];
    const float* msg_b2   = (const float*)d_in[8];
    const float* msg_W3   = (const float*)d_in[9];
    const float* msg_b3   = (const float*)d_in[10];
    const float* attn_W1  = (const float*)d_in[11];
    const float* attn_b1  = (const float*)d_in[12];
    const float* attn_W2  = (const float*)d_in[13];
    const float* attn_b2  = (const float*)d_in[14];
    const float* val_W    = (const float*)d_in[15];
    const float* val_b    = (const float*)d_in[16];
    const float* coord_W1 = (const float*)d_in[17];
    const float* coord_b1 = (const float*)d_in[18];
    const float* coord_W2 = (const float*)d_in[19];
    const float* node_W1  = (const float*)d_in[20];
    const float* node_b1  = (const float*)d_in[21];
    const float* node_ln_g= (const float*)d_in[22];
    const float* node_ln_b= (const float*)d_in[23];
    const float* node_W2  = (const float*)d_in[24];
    const float* node_b2  = (const float*)d_in[25];
    const float* edge_W1  = (const float*)d_in[26];
    const float* edge_b1  = (const float*)d_in[27];
    const float* edge_ln_g= (const float*)d_in[28];
    const float* edge_ln_b= (const float*)d_in[29];
    const float* edge_W2  = (const float*)d_in[30];
    const float* edge_b2  = (const float*)d_in[31];
    const float* nn_g     = (const float*)d_in[32];
    const float* nn_b     = (const float*)d_in[33];
    const float* en_g     = (const float*)d_in[34];
    const float* en_b     = (const float*)d_in[35];
    const float* coord_scale = (const float*)d_in[36];

    float* out = (float*)d_out;
    float* out_h = out;                                  // (2,512,64)  = 65536
    float* out_x = out + (size_t)2 * 512 * 64;           // (2,512,2)   = 2048
    float* out_e = out_x + (size_t)2 * 512 * 2;          // (2,512,512,32)

    dim3 grid(2 * 512);
    dim3 block(256);
    hipLaunchKernelGGL(egnn_fused, grid, block, 0, stream,
                       h, x, e,
                       msg_W1, msg_b1, msg_ln_g, msg_ln_b, msg_W2, msg_b2, msg_W3, msg_b3,
                       attn_W1, attn_b1, attn_W2, attn_b2, val_W, val_b,
                       coord_W1, coord_b1, coord_W2,
                       node_W1, node_b1, node_ln_g, node_ln_b, node_W2, node_b2,
                       edge_W1, edge_b1, edge_ln_g, edge_ln_b, edge_W2, edge_b2,
                       nn_g, nn_b, en_g, en_b, coord_scale,
                       out_h, out_x, out_e);
}

// Round 2
// 830.184 us; speedup vs baseline: 12.4937x; 12.4937x over previous
//
#include <hip/hip_runtime.h>
#include <math.h>

typedef __attribute__((ext_vector_type(8))) short short8;
typedef __attribute__((ext_vector_type(4))) short short4v;
typedef __attribute__((ext_vector_type(8))) unsigned short u16x8;
typedef __attribute__((ext_vector_type(4))) float f32x4;

#define NN 512
#define JT 32
#define STR 136            // LDS row stride (bf16 elems): 272B, 16B-aligned, 2-way bank aliasing only
#define BUFSZ (JT * STR)   // 4352 ushorts = 8704 B per buffer

#define TOT_W 106496       // prepacked weight elements (bf16)

__device__ __forceinline__ unsigned short f2b(float x) {
    unsigned int u = __float_as_uint(x);
    unsigned int r = (u + 0x7FFFu + ((u >> 16) & 1u)) >> 16;
    return (unsigned short)r;
}
__device__ __forceinline__ float b2f(unsigned short v) {
    return __uint_as_float(((unsigned int)v) << 16);
}
__device__ __forceinline__ float silu_f(float v) { return v / (1.f + __expf(-v)); }

__device__ __forceinline__ float block_sum(float v, float* s_red, int t) {
    s_red[t] = v;
    __syncthreads();
    for (int s = 128; s > 0; s >>= 1) {
        if (t < s) s_red[t] += s_red[t + s];
        __syncthreads();
    }
    float r = s_red[0];
    __syncthreads();
    return r;
}

// -------- weight prepack: fp32 -> bf16 A-operand fragments --------
// frag element: ws[(((ft*nK+ks)*64 + lane)*8 + jj)] = W[k][f],
//   k = ks*32 + (lane>>4)*8 + jj ; f = ft*16 + (lane&15)
__device__ __forceinline__ void frag_kf(int loc, int nK, int& k, int& f) {
    int jj = loc & 7;
    int lane = (loc >> 3) & 63;
    int fs = loc >> 9;
    int ks = fs % nK;
    int ft = fs / nK;
    k = ks * 32 + ((lane >> 4) << 3) + jj;
    f = ft * 16 + (lane & 15);
}

extern "C" __global__ void prepack_w(const float* __restrict__ msg_W1, const float* __restrict__ msg_W2,
                                     const float* __restrict__ msg_W3, const float* __restrict__ val_W,
                                     const float* __restrict__ attn_W1, const float* __restrict__ coord_W1,
                                     const float* __restrict__ edge_W1, const float* __restrict__ edge_W2,
                                     unsigned short* __restrict__ ws) {
    int idx = blockIdx.x * 256 + threadIdx.x;
    if (idx >= TOT_W) return;
    float v;
    int k, f;
    if (idx < 16384) {            // G1: msg_input-without-h_i @ W1 : rows [h_j(64)|e(32)|dist(1)|pad]
        frag_kf(idx, 4, k, f);
        v = (k <= 96) ? msg_W1[(64 + k) * 128 + f] : 0.f;
    } else if (idx < 32768) {     // G2
        frag_kf(idx - 16384, 4, k, f);
        v = msg_W2[k * 128 + f];
    } else if (idx < 49152) {     // G3
        frag_kf(idx - 32768, 4, k, f);
        v = msg_W3[k * 128 + f];
    } else if (idx < 65536) {     // val
        frag_kf(idx - 49152, 4, k, f);
        v = val_W[k * 128 + f];
    } else if (idx < 81920) {     // ac = [attn_W1 | coord_W1]
        frag_kf(idx - 65536, 4, k, f);
        v = (f < 64) ? attn_W1[k * 64 + f] : coord_W1[k * 64 + (f - 64)];
    } else if (idx < 102400) {    // edge_W1: ks 0..3 = msg part (rows 32..159), ks 4 = e part (rows 0..31)
        frag_kf(idx - 81920, 5, k, f);
        v = (k < 128) ? edge_W1[(32 + k) * 128 + f] : edge_W1[(k - 128) * 128 + f];
    } else {                      // edge_W2 (32 out)
        frag_kf(idx - 102400, 4, k, f);
        v = edge_W2[k * 32 + f];
    }
    ws[idx] = f2b(v);
}

// -------- MFMA helpers --------
struct Frag2x2 { f32x4 a[2][2]; };

__device__ __forceinline__ short8 wfrag(const unsigned short* base, int nK, int ft, int ks, int lane) {
    return *(const short8*)(base + (((ft * nK + ks) << 9) + (lane << 3)));
}

__device__ __forceinline__ void initF(Frag2x2& F, const float* bias, int ftA, int lane) {
    int q = lane >> 4;
    f32x4 bA = *(const f32x4*)(bias + ftA * 16 + q * 4);
    f32x4 bB = *(const f32x4*)(bias + (ftA + 1) * 16 + q * 4);
    F.a[0][0] = bA; F.a[0][1] = bA;
    F.a[1][0] = bB; F.a[1][1] = bB;
}

__device__ __forceinline__ void mfma_step(Frag2x2& F, const unsigned short* wbase, int nK, int ks,
                                          int ftA, const unsigned short* sbuf, int kcol, int lane) {
    int q8 = ((lane >> 4) << 3), l15 = lane & 15;
    short8 b0 = *(const short8*)(sbuf + l15 * STR + kcol + q8);
    short8 b1 = *(const short8*)(sbuf + (16 + l15) * STR + kcol + q8);
    short8 a0 = wfrag(wbase, nK, ftA, ks, lane);
    short8 a1 = wfrag(wbase, nK, ftA + 1, ks, lane);
    F.a[0][0] = __builtin_amdgcn_mfma_f32_16x16x32_bf16(a0, b0, F.a[0][0], 0, 0, 0);
    F.a[0][1] = __builtin_amdgcn_mfma_f32_16x16x32_bf16(a0, b1, F.a[0][1], 0, 0, 0);
    F.a[1][0] = __builtin_amdgcn_mfma_f32_16x16x32_bf16(a1, b0, F.a[1][0], 0, 0, 0);
    F.a[1][1] = __builtin_amdgcn_mfma_f32_16x16x32_bf16(a1, b1, F.a[1][1], 0, 0, 0);
}

__device__ __forceinline__ void storeF(const Frag2x2& F, unsigned short* dbuf, int ftA, int lane, int act) {
    int q = lane >> 4, l15 = lane & 15;
#pragma unroll
    for (int fi = 0; fi < 2; fi++)
#pragma unroll
        for (int ji = 0; ji < 2; ji++) {
            int j = ji * 16 + l15;
            int f0 = (ftA + fi) * 16 + q * 4;
            f32x4 v = F.a[fi][ji];
            short4v p;
#pragma unroll
            for (int r = 0; r < 4; r++) {
                float o = act ? silu_f(v[r]) : v[r];
                p[r] = (short)f2b(o);
            }
            *(short4v*)(dbuf + j * STR + f0) = p;
        }
}

// LayerNorm over 128 features (bf16 rows, fp32 math). t -> (j=t>>3, sub=t&7), 16 feats each.
__device__ __forceinline__ void ln_tile(unsigned short* buf, const float* g, const float* bv, int t) {
    int j = t >> 3, sub = t & 7;
    unsigned short* p = buf + j * STR + sub * 16;
    u16x8 r0 = *(u16x8*)p;
    u16x8 r1 = *(u16x8*)(p + 8);
    float v[16];
#pragma unroll
    for (int i = 0; i < 8; i++) { v[i] = b2f(r0[i]); v[8 + i] = b2f(r1[i]); }
    float sm = 0.f;
#pragma unroll
    for (int i = 0; i < 16; i++) sm += v[i];
    sm += __shfl_xor(sm, 1); sm += __shfl_xor(sm, 2); sm += __shfl_xor(sm, 4);
    float mean = sm * 0.0078125f;
    float sq = 0.f;
#pragma unroll
    for (int i = 0; i < 16; i++) { float d = v[i] - mean; sq += d * d; }
    sq += __shfl_xor(sq, 1); sq += __shfl_xor(sq, 2); sq += __shfl_xor(sq, 4);
    float rstd = rsqrtf(sq * 0.0078125f + 1e-5f);
    u16x8 o0, o1;
#pragma unroll
    for (int i = 0; i < 8; i++) {
        o0[i] = f2b((v[i] - mean) * rstd * g[sub * 16 + i] + bv[sub * 16 + i]);
        o1[i] = f2b((v[8 + i] - mean) * rstd * g[sub * 16 + 8 + i] + bv[sub * 16 + 8 + i]);
    }
    *(u16x8*)p = o0;
    *(u16x8*)(p + 8) = o1;
}

extern "C" __global__ __launch_bounds__(256, 2)
void egnn_mfma(const float* __restrict__ h, const float* __restrict__ x, const float* __restrict__ e,
               const float* __restrict__ msg_W1, const float* __restrict__ msg_b1,
               const float* __restrict__ msg_ln_g, const float* __restrict__ msg_ln_b,
               const float* __restrict__ msg_b2, const float* __restrict__ msg_b3,
               const float* __restrict__ attn_b1, const float* __restrict__ attn_W2,
               const float* __restrict__ attn_b2, const float* __restrict__ val_b,
               const float* __restrict__ coord_b1, const float* __restrict__ coord_W2,
               const float* __restrict__ node_W1, const float* __restrict__ node_b1,
               const float* __restrict__ node_ln_g, const float* __restrict__ node_ln_b,
               const float* __restrict__ node_W2, const float* __restrict__ node_b2,
               const float* __restrict__ edge_b1, const float* __restrict__ edge_ln_g,
               const float* __restrict__ edge_ln_b, const float* __restrict__ edge_b2,
               const float* __restrict__ nn_g, const float* __restrict__ nn_b,
               const float* __restrict__ en_g, const float* __restrict__ en_b,
               const float* __restrict__ coord_scale_p,
               const unsigned short* __restrict__ wpk,
               float* __restrict__ out_h, float* __restrict__ out_x, float* __restrict__ out_e) {
    const int t = threadIdx.x;
    const int wave = t >> 6, lane = t & 63;
    const int bi = blockIdx.x;
    const int b = bi >> 9;

    __shared__ __align__(16) unsigned short sm[4 * BUFSZ];
    unsigned short* B0 = sm;
    unsigned short* B1 = sm + BUFSZ;
    unsigned short* B2 = sm + 2 * BUFSZ;
    unsigned short* B3 = sm + 3 * BUFSZ;

    __shared__ __align__(16) float s_bias1[128], s_b2c[128], s_b3c[128], s_bv[128], s_bac[128], s_be1[128];
    __shared__ __align__(16) float s_be2[32];
    __shared__ __align__(16) float s_mg[128], s_mb[128], s_eg[128], s_eb[128];
    __shared__ __align__(16) float s_cw2[64], s_aw2[4][64], s_ab2[4], s_eng[32], s_enb[32];
    __shared__ __align__(16) float s_logit[JT][4];
    __shared__ __align__(16) float s_hi[64];
    __shared__ __align__(16) float s_ep[576];  // 192 hin | 128 nh | 256 red

    const unsigned short* wG1 = wpk;
    const unsigned short* wG2 = wpk + 16384;
    const unsigned short* wG3 = wpk + 32768;
    const unsigned short* wV  = wpk + 49152;
    const unsigned short* wAC = wpk + 65536;
    const unsigned short* wE1 = wpk + 81920;
    const unsigned short* wE2 = wpk + 102400;

    // ---- stage params ----
    if (t < 64) s_hi[t] = h[(size_t)bi * 64 + t];
    if (t < 128) {
        s_b2c[t] = msg_b2[t]; s_b3c[t] = msg_b3[t]; s_bv[t] = val_b[t];
        s_bac[t] = (t < 64) ? attn_b1[t] : coord_b1[t - 64];
        s_be1[t] = edge_b1[t];
        s_mg[t] = msg_ln_g[t]; s_mb[t] = msg_ln_b[t];
        s_eg[t] = edge_ln_g[t]; s_eb[t] = edge_ln_b[t];
    }
    if (t < 32) { s_be2[t] = edge_b2[t]; s_eng[t] = en_g[t]; s_enb[t] = en_b[t]; }
    if (t < 64) s_cw2[t] = coord_W2[t];
    { int hh = t >> 6, k = t & 63; s_aw2[hh][k] = attn_W2[k * 4 + hh]; }
    if (t < 4) s_ab2[t] = attn_b2[t];
    __syncthreads();
    // bias1' = msg_b1 + h_i @ W1[0:64]  (fp32, exact)
    if (t < 128) {
        float acc = msg_b1[t];
        for (int k = 0; k < 64; k++) acc = fmaf(s_hi[k], msg_W1[k * 128 + t], acc);
        s_bias1[t] = acc;
    }
    const float xi0 = x[(size_t)bi * 2 + 0];
    const float xi1 = x[(size_t)bi * 2 + 1];

    float m_run = -3e38f, l_run = 0.f, acc_run = 0.f;   // t<128: f=t, head=t>>5
    const int sm_h = (t >> 5) & 3;
    float cu_x = 0.f, cu_y = 0.f, xdn_x = 0.f, xdn_y = 0.f;

    const int q8 = ((lane >> 4) << 3), l15 = lane & 15;

    for (int j0 = 0; j0 < NN; j0 += JT) {
        // ---- stage B0: [h_j(0:64) | e(64:96) | dist(96) | zeros(97:128)] ----
        {
            int j = t >> 3, sub = t & 7;
            int jj = j0 + j;
            const float* hp = h + ((size_t)(b * NN + jj)) * 64 + sub * 8;
            float4 h0 = *(const float4*)hp;
            float4 h1 = *(const float4*)(hp + 4);
            u16x8 o;
            o[0] = f2b(h0.x); o[1] = f2b(h0.y); o[2] = f2b(h0.z); o[3] = f2b(h0.w);
            o[4] = f2b(h1.x); o[5] = f2b(h1.y); o[6] = f2b(h1.z); o[7] = f2b(h1.w);
            *(u16x8*)(B0 + j * STR + sub * 8) = o;
            if (sub < 4) {
                const float* epp = e + ((size_t)bi * NN + jj) * 32 + sub * 8;
                float4 e0 = *(const float4*)epp;
                float4 e1 = *(const float4*)(epp + 4);
                u16x8 oe;
                oe[0] = f2b(e0.x); oe[1] = f2b(e0.y); oe[2] = f2b(e0.z); oe[3] = f2b(e0.w);
                oe[4] = f2b(e1.x); oe[5] = f2b(e1.y); oe[6] = f2b(e1.z); oe[7] = f2b(e1.w);
                *(u16x8*)(B0 + j * STR + 64 + sub * 8) = oe;
            } else if (sub > 4) {
                u16x8 z = (u16x8)0;
                *(u16x8*)(B0 + j * STR + 96 + (sub - 4) * 8) = z;   // cols 104..127
            }
        }
        if (t < JT) {
            int jj = j0 + t;
            float dx = x[(size_t)(b * NN + jj) * 2 + 0] - xi0;
            float dy = x[(size_t)(b * NN + jj) * 2 + 1] - xi1;
            float dist = sqrtf(dx * dx + dy * dy);
            float inv = 1.f / (dist + 1e-8f);
            xdn_x = dx * inv; xdn_y = dy * inv;
            u16x8 z = (u16x8)0;
            z[0] = f2b(dist);
            *(u16x8*)(B0 + t * STR + 96) = z;                        // dist + zeros 97..103
        }
        __syncthreads();

        // ---- G1: silu( [h_j|e|dist] @ W1' + bias1' ) -> B1 ----
        {
            Frag2x2 F; initF(F, s_bias1, wave * 2, lane);
#pragma unroll
            for (int ks = 0; ks < 4; ks++) mfma_step(F, wG1, 4, ks, wave * 2, B0, ks * 32, lane);
            storeF(F, B1, wave * 2, lane, 1);
        }
        __syncthreads();
        ln_tile(B1, s_mg, s_mb, t);
        __syncthreads();

        // ---- G2: silu(B1 @ W2 + b2) -> B2 ----
        {
            Frag2x2 F; initF(F, s_b2c, wave * 2, lane);
#pragma unroll
            for (int ks = 0; ks < 4; ks++) mfma_step(F, wG2, 4, ks, wave * 2, B1, ks * 32, lane);
            storeF(F, B2, wave * 2, lane, 1);
        }
        __syncthreads();

        // ---- G3: B2 @ W3 + b3 -> B3 (messages) ----
        {
            Frag2x2 F; initF(F, s_b3c, wave * 2, lane);
#pragma unroll
            for (int ks = 0; ks < 4; ks++) mfma_step(F, wG3, 4, ks, wave * 2, B2, ks * 32, lane);
            storeF(F, B3, wave * 2, lane, 0);
        }
        __syncthreads();

        // ---- fused E: values / [attn|coord]-hidden / edge-hidden from messages ----
        {
            Frag2x2 FV, FA, FE;
            initF(FV, s_bv, wave * 2, lane);
            initF(FA, s_bac, wave * 2, lane);
            initF(FE, s_be1, wave * 2, lane);
#pragma unroll
            for (int ks = 0; ks < 4; ks++) {
                short8 b0 = *(const short8*)(B3 + l15 * STR + ks * 32 + q8);
                short8 b1 = *(const short8*)(B3 + (16 + l15) * STR + ks * 32 + q8);
                short8 av0 = wfrag(wV, 4, wave * 2, ks, lane);
                short8 av1 = wfrag(wV, 4, wave * 2 + 1, ks, lane);
                FV.a[0][0] = __builtin_amdgcn_mfma_f32_16x16x32_bf16(av0, b0, FV.a[0][0], 0, 0, 0);
                FV.a[0][1] = __builtin_amdgcn_mfma_f32_16x16x32_bf16(av0, b1, FV.a[0][1], 0, 0, 0);
                FV.a[1][0] = __builtin_amdgcn_mfma_f32_16x16x32_bf16(av1, b0, FV.a[1][0], 0, 0, 0);
                FV.a[1][1] = __builtin_amdgcn_mfma_f32_16x16x32_bf16(av1, b1, FV.a[1][1], 0, 0, 0);
                short8 aa0 = wfrag(wAC, 4, wave * 2, ks, lane);
                short8 aa1 = wfrag(wAC, 4, wave * 2 + 1, ks, lane);
                FA.a[0][0] = __builtin_amdgcn_mfma_f32_16x16x32_bf16(aa0, b0, FA.a[0][0], 0, 0, 0);
                FA.a[0][1] = __builtin_amdgcn_mfma_f32_16x16x32_bf16(aa0, b1, FA.a[0][1], 0, 0, 0);
                FA.a[1][0] = __builtin_amdgcn_mfma_f32_16x16x32_bf16(aa1, b0, FA.a[1][0], 0, 0, 0);
                FA.a[1][1] = __builtin_amdgcn_mfma_f32_16x16x32_bf16(aa1, b1, FA.a[1][1], 0, 0, 0);
                short8 ae0 = wfrag(wE1, 5, wave * 2, ks, lane);
                short8 ae1 = wfrag(wE1, 5, wave * 2 + 1, ks, lane);
                FE.a[0][0] = __builtin_amdgcn_mfma_f32_16x16x32_bf16(ae0, b0, FE.a[0][0], 0, 0, 0);
                FE.a[0][1] = __builtin_amdgcn_mfma_f32_16x16x32_bf16(ae0, b1, FE.a[0][1], 0, 0, 0);
                FE.a[1][0] = __builtin_amdgcn_mfma_f32_16x16x32_bf16(ae1, b0, FE.a[1][0], 0, 0, 0);
                FE.a[1][1] = __builtin_amdgcn_mfma_f32_16x16x32_bf16(ae1, b1, FE.a[1][1], 0, 0, 0);
            }
            {   // edge-hidden e-part: rows 0..31 of edge_W1 against B0 cols 64..95
                short8 b0 = *(const short8*)(B0 + l15 * STR + 64 + q8);
                short8 b1 = *(const short8*)(B0 + (16 + l15) * STR + 64 + q8);
                short8 a0 = wfrag(wE1, 5, wave * 2, 4, lane);
                short8 a1 = wfrag(wE1, 5, wave * 2 + 1, 4, lane);
                FE.a[0][0] = __builtin_amdgcn_mfma_f32_16x16x32_bf16(a0, b0, FE.a[0][0], 0, 0, 0);
                FE.a[0][1] = __builtin_amdgcn_mfma_f32_16x16x32_bf16(a0, b1, FE.a[0][1], 0, 0, 0);
                FE.a[1][0] = __builtin_amdgcn_mfma_f32_16x16x32_bf16(a1, b0, FE.a[1][0], 0, 0, 0);
                FE.a[1][1] = __builtin_amdgcn_mfma_f32_16x16x32_bf16(a1, b1, FE.a[1][1], 0, 0, 0);
            }
            __syncthreads();   // all reads of B0/B3 done before overwrite
            storeF(FV, B1, wave * 2, lane, 0);   // values
            storeF(FA, B2, wave * 2, lane, 1);   // [attn-hidden | coord-hidden], silu
            storeF(FE, B0, wave * 2, lane, 1);   // edge hidden, silu
        }
        __syncthreads();

        ln_tile(B0, s_eg, s_eb, t);              // edge LN
        __syncthreads();

        // ---- attn logits ----
        if (t < 128) {
            int j = t >> 2, hh = t & 3;
            float acc = s_ab2[hh];
#pragma unroll
            for (int m = 0; m < 8; m++) {
                u16x8 r = *(u16x8*)(B2 + j * STR + m * 8);
#pragma unroll
                for (int i = 0; i < 8; i++) acc = fmaf(b2f(r[i]), s_aw2[hh][m * 8 + i], acc);
            }
            s_logit[j][hh] = acc * 0.17677669529663687f;  // 1/sqrt(32)
        }
        __syncthreads();

        // ---- waves 0,1: online softmax + coord ;  waves 2,3: edge2 GEMM ----
        if (wave < 2) {
#pragma unroll 4
            for (int j = 0; j < JT; j++) {
                float lg = s_logit[j][sm_h];
                float nm = fmaxf(m_run, lg);
                float sc = __expf(m_run - nm);
                float p = __expf(lg - nm);
                float v = b2f(B1[j * STR + t]);
                acc_run = acc_run * sc + p * v;
                l_run = l_run * sc + p;
                m_run = nm;
            }
            if (t < 32) {
                float acc = 0.f;
#pragma unroll
                for (int m = 0; m < 8; m++) {
                    u16x8 r = *(u16x8*)(B2 + t * STR + 64 + m * 8);
#pragma unroll
                    for (int i = 0; i < 8; i++) acc = fmaf(b2f(r[i]), s_cw2[m * 8 + i], acc);
                }
                float cw = tanhf(acc * 0.1f);
                cu_x = fmaf(cw, xdn_x, cu_x);
                cu_y = fmaf(cw, xdn_y, cu_y);
            }
        } else {
            int wv = wave - 2;   // f-tile 0 or 1 of the 32-wide edge output
            int q = lane >> 4;
            f32x4 bb = *(const f32x4*)(s_be2 + wv * 16 + q * 4);
            f32x4 a0 = bb, a1 = bb;
#pragma unroll
            for (int ks = 0; ks < 4; ks++) {
                short8 b0 = *(const short8*)(B0 + l15 * STR + ks * 32 + q8);
                short8 b1 = *(const short8*)(B0 + (16 + l15) * STR + ks * 32 + q8);
                short8 aw = wfrag(wE2, 4, wv, ks, lane);
                a0 = __builtin_amdgcn_mfma_f32_16x16x32_bf16(aw, b0, a0, 0, 0, 0);
                a1 = __builtin_amdgcn_mfma_f32_16x16x32_bf16(aw, b1, a1, 0, 0, 0);
            }
#pragma unroll
            for (int ji = 0; ji < 2; ji++) {
                int j = ji * 16 + l15;
                int f0 = wv * 16 + q * 4;
                f32x4 v = ji ? a1 : a0;
                short4v p;
#pragma unroll
                for (int r = 0; r < 4; r++) p[r] = (short)f2b(v[r]);
                *(short4v*)(B3 + j * STR + f0) = p;
            }
        }
        __syncthreads();

        // ---- e_new = LN(e + ee), write out ----
        {
            int j = t >> 3, sub = t & 7;
            int jj = j0 + j;
            float4 ev = *(const float4*)(e + ((size_t)bi * NN + jj) * 32 + sub * 4);
            unsigned short* p = B3 + j * STR + sub * 4;
            float v0 = ev.x + b2f(p[0]);
            float v1 = ev.y + b2f(p[1]);
            float v2 = ev.z + b2f(p[2]);
            float v3 = ev.w + b2f(p[3]);
            float s = v0 + v1 + v2 + v3;
            s += __shfl_xor(s, 1); s += __shfl_xor(s, 2); s += __shfl_xor(s, 4);
            float mean = s * 0.03125f;
            float d0 = v0 - mean, d1 = v1 - mean, d2 = v2 - mean, d3 = v3 - mean;
            float sq = d0 * d0 + d1 * d1 + d2 * d2 + d3 * d3;
            sq += __shfl_xor(sq, 1); sq += __shfl_xor(sq, 2); sq += __shfl_xor(sq, 4);
            float rstd = rsqrtf(sq * 0.03125f + 1e-5f);
            float4 o;
            o.x = d0 * rstd * s_eng[sub * 4 + 0] + s_enb[sub * 4 + 0];
            o.y = d1 * rstd * s_eng[sub * 4 + 1] + s_enb[sub * 4 + 1];
            o.z = d2 * rstd * s_eng[sub * 4 + 2] + s_enb[sub * 4 + 2];
            o.w = d3 * rstd * s_eng[sub * 4 + 3] + s_enb[sub * 4 + 3];
            *(float4*)(out_e + ((size_t)bi * NN + jj) * 32 + sub * 4) = o;
        }
        __syncthreads();
    }

    // ================= node & coord epilogue =================
    float* s_hin = s_ep;          // 192
    float* s_nh  = s_ep + 192;    // 128
    float* s_red = s_ep + 320;    // 256

    if (t < 128) s_hin[64 + t] = acc_run / l_run;   // messages_attended
    if (t < 64) s_hin[t] = s_hi[t];
    __syncthreads();

    if (t < 128) {
        float acc = node_b1[t];
        for (int k4 = 0; k4 < 48; k4++) {
            float4 iv = *(const float4*)&s_hin[k4 * 4];
            acc = fmaf(iv.x, node_W1[(k4 * 4 + 0) * 128 + t], acc);
            acc = fmaf(iv.y, node_W1[(k4 * 4 + 1) * 128 + t], acc);
            acc = fmaf(iv.z, node_W1[(k4 * 4 + 2) * 128 + t], acc);
            acc = fmaf(iv.w, node_W1[(k4 * 4 + 3) * 128 + t], acc);
        }
        s_nh[t] = silu_f(acc);
    }
    __syncthreads();
    {
        float v = (t < 128) ? s_nh[t] : 0.f;
        float mean = block_sum(v, s_red, t) * 0.0078125f;
        float d = (t < 128) ? (v - mean) : 0.f;
        float var = block_sum(d * d, s_red, t) * 0.0078125f;
        float rstd = rsqrtf(var + 1e-5f);
        if (t < 128) s_nh[t] = d * rstd * node_ln_g[t] + node_ln_b[t];
    }
    __syncthreads();
    if (t < 64) {
        float acc = node_b2[t];
        for (int k4 = 0; k4 < 32; k4++) {
            float4 iv = *(const float4*)&s_nh[k4 * 4];
            acc = fmaf(iv.x, node_W2[(k4 * 4 + 0) * 64 + t], acc);
            acc = fmaf(iv.y, node_W2[(k4 * 4 + 1) * 64 + t], acc);
            acc = fmaf(iv.z, node_W2[(k4 * 4 + 2) * 64 + t], acc);
            acc = fmaf(iv.w, node_W2[(k4 * 4 + 3) * 64 + t], acc);
        }
        s_hin[t] = acc + s_hi[t];
    }
    __syncthreads();
    {
        float v = (t < 64) ? s_hin[t] : 0.f;
        float mean = block_sum(v, s_red, t) * 0.015625f;
        float d = (t < 64) ? (v - mean) : 0.f;
        float var = block_sum(d * d, s_red, t) * 0.015625f;
        float rstd = rsqrtf(var + 1e-5f);
        if (t < 64) out_h[(size_t)bi * 64 + t] = d * rstd * nn_g[t] + nn_b[t];
    }

    if (t < 32) {
        cu_x += __shfl_xor(cu_x, 16); cu_x += __shfl_xor(cu_x, 8);
        cu_x += __shfl_xor(cu_x, 4);  cu_x += __shfl_xor(cu_x, 2); cu_x += __shfl_xor(cu_x, 1);
        cu_y += __shfl_xor(cu_y, 16); cu_y += __shfl_xor(cu_y, 8);
        cu_y += __shfl_xor(cu_y, 4);  cu_y += __shfl_xor(cu_y, 2); cu_y += __shfl_xor(cu_y, 1);
        if (t == 0) {
            float scl = coord_scale_p[0];
            out_x[(size_t)bi * 2 + 0] = xi0 + scl * cu_x;
            out_x[(size_t)bi * 2 + 1] = xi1 + scl * cu_y;
        }
    }
}

extern "C" void kernel_launch(void* const* d_in, const int* in_sizes, int n_in,
                              void* d_out, int out_size, void* d_ws, size_t ws_size,
                              hipStream_t stream) {
    const float* h        = (const float*)d_in[0];
    const float* x        = (const float*)d_in[1];
    const float* e        = (const float*)d_in[2];
    const float* msg_W1   = (const float*)d_in[3];
    const float* msg_b1   = (const float*)d_in[4];
    const float* msg_ln_g = (const float*)d_in[5];
    const float* msg_ln_b = (const float*)d_in[6];
    const float* msg_W2   = (const float*)d_in[7];
    const float* msg_b2   = (const float*)d_in[8];
    const float* msg_W3   = (const float*)d_in[9];
    const float* msg_b3   = (const float*)d_in[10];
    const float* attn_W1  = (const float*)d_in[11];
    const float* attn_b1  = (const float*)d_in[12];
    const float* attn_W2  = (const float*)d_in[13];
    const float* attn_b2  = (const float*)d_in[14];
    const float* val_W    = (const float*)d_in[15];
    const float* val_b    = (const float*)d_in[16];
    const float* coord_W1 = (const float*)d_in[17];
    const float* coord_b1 = (const float*)d_in[18];
    const float* coord_W2 = (const float*)d_in[19];
    const float* node_W1  = (const float*)d_in[20];
    const float* node_b1  = (const float*)d_in[21];
    const float* node_ln_g= (const float*)d_in[22];
    const float* node_ln_b= (const float*)d_in[23];
    const float* node_W2  = (const float*)d_in[24];
    const float* node_b2  = (const float*)d_in[25];
    const float* edge_W1  = (const float*)d_in[26];
    const float* edge_b1  = (const float*)d_in[27];
    const float* edge_ln_g= (const float*)d_in[28];
    const float* edge_ln_b= (const float*)d_in[29];
    const float* edge_W2  = (const float*)d_in[30];
    const float* edge_b2  = (const float*)d_in[31];
    const float* nn_g     = (const float*)d_in[32];
    const float* nn_b     = (const float*)d_in[33];
    const float* en_g     = (const float*)d_in[34];
    const float* en_b     = (const float*)d_in[35];
    const float* coord_scale = (const float*)d_in[36];

    unsigned short* wpk = (unsigned short*)d_ws;

    float* out = (float*)d_out;
    float* out_h = out;
    float* out_x = out + (size_t)2 * 512 * 64;
    float* out_e = out_x + (size_t)2 * 512 * 2;

    hipLaunchKernelGGL(prepack_w, dim3((TOT_W + 255) / 256), dim3(256), 0, stream,
                       msg_W1, msg_W2, msg_W3, val_W, attn_W1, coord_W1, edge_W1, edge_W2, wpk);

    hipLaunchKernelGGL(egnn_mfma, dim3(2 * 512), dim3(256), 0, stream,
                       h, x, e,
                       msg_W1, msg_b1, msg_ln_g, msg_ln_b, msg_b2, msg_b3,
                       attn_b1, attn_W2, attn_b2, val_b, coord_b1, coord_W2,
                       node_W1, node_b1, node_ln_g, node_ln_b, node_W2, node_b2,
                       edge_b1, edge_ln_g, edge_ln_b, edge_b2,
                       nn_g, nn_b, en_g, en_b, coord_scale,
                       wpk, out_h, out_x, out_e);
}